// Round 11
// baseline (279.245 us; speedup 1.0000x reference)
//
#include <hip/hip_runtime.h>
#include <cstdint>
#include <cstddef>

#define NN 50000
#define EE 500000
#define RR 8
#define CC 128
#define BB 4
#define H3C 384
#define NB 196  // ceil(NN/256)
#define YS 64.0f
#define YSI (1.0f / 64.0f)

typedef unsigned short ushort_t;
typedef __bf16 bf16x8 __attribute__((ext_vector_type(8)));
typedef float f32x4 __attribute__((ext_vector_type(4)));
typedef float f32x2 __attribute__((ext_vector_type(2)));
typedef unsigned short u16x8 __attribute__((ext_vector_type(8)));

static __device__ __forceinline__ ushort_t f2bf(float f) {
  unsigned u = __float_as_uint(f);
  unsigned r = (u + 0x7fffu + ((u >> 16) & 1u)) >> 16;
  return (ushort_t)r;
}
static __device__ __forceinline__ float bf2f(ushort_t u) {
  return __uint_as_float(((unsigned)u) << 16);
}

// accumulate 8 fp8 channels (2 dwords) with weight w
static __device__ __forceinline__ void acc8(float* a, unsigned vx, unsigned vy, float w) {
  f32x2 t;
  t = __builtin_amdgcn_cvt_pk_f32_fp8(vx, false); a[0] += w * t.x; a[1] += w * t.y;
  t = __builtin_amdgcn_cvt_pk_f32_fp8(vx, true);  a[2] += w * t.x; a[3] += w * t.y;
  t = __builtin_amdgcn_cvt_pk_f32_fp8(vy, false); a[4] += w * t.x; a[5] += w * t.y;
  t = __builtin_amdgcn_cvt_pk_f32_fp8(vy, true);  a[6] += w * t.x; a[7] += w * t.y;
}

__global__ void zero_int_k(int* p, int n) {
  int i = blockIdx.x * 256 + threadIdx.x;
  if (i < n) p[i] = 0;
}

__global__ void count_k(const int* __restrict__ ei, const int* __restrict__ et, int* cnt) {
  int e = blockIdx.x * 256 + threadIdx.x;
  if (e >= EE) return;
  int d = ei[EE + e];
  int r = et[e];
  atomicAdd(&cnt[r * NN + d], 1);
}

__global__ __launch_bounds__(256) void scanA_k(const int* __restrict__ cnt_rd, int* off, int* bsum) {
  __shared__ int s[256];
  int t = threadIdx.x;
  int i = blockIdx.x * 256 + t;
  int v = 0;
  if (i < NN) {
#pragma unroll
    for (int r = 0; r < RR; ++r) v += cnt_rd[r * NN + i];
  }
  s[t] = v;
  __syncthreads();
  for (int d = 1; d < 256; d <<= 1) {
    int x = (t >= d) ? s[t - d] : 0;
    __syncthreads();
    s[t] += x;
    __syncthreads();
  }
  if (i < NN) off[i] = s[t] - v;
  if (t == 255) bsum[blockIdx.x] = s[255];
}

__global__ __launch_bounds__(256) void scanB_k(const int* __restrict__ bsum, int* bbase) {
  __shared__ int s[256];
  int t = threadIdx.x;
  int v = (t < NB) ? bsum[t] : 0;
  s[t] = v;
  __syncthreads();
  for (int d = 1; d < 256; d <<= 1) {
    int x = (t >= d) ? s[t - d] : 0;
    __syncthreads();
    s[t] += x;
    __syncthreads();
  }
  if (t < NB) bbase[t] = s[t] - v;
}

// finalize offsets AND pre-load cursor array with the start offset
__global__ void scanC_k(int* off, const int* __restrict__ bbase, int* cur) {
  int i = blockIdx.x * 256 + threadIdx.x;
  if (i < NN) {
    int v = off[i] + bbase[i >> 8];
    off[i] = v;
    cur[i] = v;
  }
  if (i == 0) off[NN] = EE;
}

// Scatter edges into CSR slots; payload = {src | (r<<20), bits(1/max(cnt_rd,1))}.
__global__ void fill_k(const int* __restrict__ ei, const int* __restrict__ et,
                       const int* __restrict__ cnt_rd, int* cur, uint2* __restrict__ payload) {
  int e = blockIdx.x * 256 + threadIdx.x;
  if (e >= EE) return;
  int s = ei[e], d = ei[EE + e], r = et[e];
  int pos = atomicAdd(&cur[d], 1);
  float w = 1.0f / (float)max(cnt_rd[r * NN + d], 1);
  payload[pos] = make_uint2((unsigned)s | ((unsigned)r << 20), __float_as_uint(w));
}

// Layer-1 message table: hrq[r][n][c] = fp8(YS * sum_b comp1[r][b]*basis1[b][n][c])
__global__ void makehr1q_k(const float* __restrict__ basis1, const float* __restrict__ comp1,
                           unsigned char* __restrict__ hrq) {
  __shared__ float comps[RR * BB];
  if (threadIdx.x < RR * BB) comps[threadIdx.x] = comp1[threadIdx.x] * YS;
  __syncthreads();
  int idx = blockIdx.x * 256 + threadIdx.x;  // n*32 + c4
  if (idx >= NN * 32) return;
  int n = idx >> 5, c0 = (idx & 31) * 4;
  float4 y[BB];
#pragma unroll
  for (int b = 0; b < BB; ++b)
    y[b] = *(const float4*)(basis1 + ((size_t)b * NN + n) * CC + c0);
#pragma unroll
  for (int r = 0; r < RR; ++r) {
    float k0 = comps[r * BB + 0], k1 = comps[r * BB + 1];
    float k2 = comps[r * BB + 2], k3 = comps[r * BB + 3];
    float v0 = k0 * y[0].x + k1 * y[1].x + k2 * y[2].x + k3 * y[3].x;
    float v1 = k0 * y[0].y + k1 * y[1].y + k2 * y[2].y + k3 * y[3].y;
    float v2 = k0 * y[0].z + k1 * y[1].z + k2 * y[2].z + k3 * y[3].z;
    float v3 = k0 * y[0].w + k1 * y[1].w + k2 * y[2].w + k3 * y[3].w;
    int pk = __builtin_amdgcn_cvt_pk_fp8_f32(v0, v1, 0, false);
    pk = __builtin_amdgcn_cvt_pk_fp8_f32(v2, v3, pk, true);
    *(unsigned*)(hrq + ((size_t)r * NN + n) * CC + c0) = (unsigned)pk;
  }
}

// Layers 2/3 message table: hrq[r][n][c] = fp8( sum_b comp[r][b] * yq_b[n][c] )
__global__ void makehrq_k(const unsigned char* __restrict__ yq, const float* __restrict__ comp,
                          unsigned char* __restrict__ hrq) {
  __shared__ float comps[RR * BB];
  if (threadIdx.x < RR * BB) comps[threadIdx.x] = comp[threadIdx.x];
  __syncthreads();
  int idx = blockIdx.x * 256 + threadIdx.x;  // n*32 + c4
  if (idx >= NN * 32) return;
  int n = idx >> 5, c0 = (idx & 31) * 4;
  const unsigned char* yr = yq + (size_t)n * 512 + c0;
  float y[BB][4];
#pragma unroll
  for (int b = 0; b < BB; ++b) {
    unsigned u = *(const unsigned*)(yr + b * 128);
    f32x2 lo = __builtin_amdgcn_cvt_pk_f32_fp8(u, false);
    f32x2 hi = __builtin_amdgcn_cvt_pk_f32_fp8(u, true);
    y[b][0] = lo.x; y[b][1] = lo.y; y[b][2] = hi.x; y[b][3] = hi.y;
  }
#pragma unroll
  for (int r = 0; r < RR; ++r) {
    float k0 = comps[r * BB + 0], k1 = comps[r * BB + 1];
    float k2 = comps[r * BB + 2], k3 = comps[r * BB + 3];
    float v0 = k0 * y[0][0] + k1 * y[1][0] + k2 * y[2][0] + k3 * y[3][0];
    float v1 = k0 * y[0][1] + k1 * y[1][1] + k2 * y[2][1] + k3 * y[3][1];
    float v2 = k0 * y[0][2] + k1 * y[1][2] + k2 * y[2][2] + k3 * y[3][2];
    float v3 = k0 * y[0][3] + k1 * y[1][3] + k2 * y[2][3] + k3 * y[3][3];
    int pk = __builtin_amdgcn_cvt_pk_fp8_f32(v0, v1, 0, false);
    pk = __builtin_amdgcn_cvt_pk_fp8_f32(v2, v3, pk, true);
    *(unsigned*)(hrq + ((size_t)r * NN + n) * CC + c0) = (unsigned)pk;
  }
}

// Aggregation: one wave per node; 4 quarter-wave groups each own an edge
// stream (4 edges in flight); lane handles 8 channels (8B gather per edge).
template <bool ROOTF32>
__global__ __launch_bounds__(256) void aggrq_k(const int* __restrict__ off,
                                               const uint2* __restrict__ payload,
                                               const unsigned char* __restrict__ hrq,
                                               const float* __restrict__ rootf,
                                               const ushort_t* __restrict__ rootb,
                                               const float* __restrict__ bias,
                                               ushort_t* __restrict__ xbw, int xoff) {
  int wave = threadIdx.x >> 6, lane = threadIdx.x & 63;
  int d = blockIdx.x * 4 + wave;
  if (d >= NN) return;
  int beg = off[d], end = off[d + 1];
  int g = lane >> 4, q = lane & 15;
  int c0 = q * 8;
  float a[8] = {};
  int i = beg + g;
  for (; i + 4 < end; i += 8) {
    uint2 pA = payload[i], pB = payload[i + 4];
    uint2 vA = *(const uint2*)(hrq + ((size_t)(pA.x >> 20) * NN + (pA.x & 0xFFFFFu)) * CC + c0);
    uint2 vB = *(const uint2*)(hrq + ((size_t)(pB.x >> 20) * NN + (pB.x & 0xFFFFFu)) * CC + c0);
    acc8(a, vA.x, vA.y, __uint_as_float(pA.y));
    acc8(a, vB.x, vB.y, __uint_as_float(pB.y));
  }
  if (i < end) {
    uint2 p = payload[i];
    uint2 v = *(const uint2*)(hrq + ((size_t)(p.x >> 20) * NN + (p.x & 0xFFFFFu)) * CC + c0);
    acc8(a, v.x, v.y, __uint_as_float(p.y));
  }
#pragma unroll
  for (int j = 0; j < 8; ++j) {
    a[j] += __shfl_xor(a[j], 16);
    a[j] += __shfl_xor(a[j], 32);
  }
  if (g == 0) {
    float rt[8];
    if (ROOTF32) {
      float4 r0 = *(const float4*)(rootf + (size_t)d * CC + c0);
      float4 r1 = *(const float4*)(rootf + (size_t)d * CC + c0 + 4);
      rt[0] = r0.x; rt[1] = r0.y; rt[2] = r0.z; rt[3] = r0.w;
      rt[4] = r1.x; rt[5] = r1.y; rt[6] = r1.z; rt[7] = r1.w;
    } else {
      u16x8 u = *(const u16x8*)(rootb + (size_t)d * CC + c0);
#pragma unroll
      for (int j = 0; j < 8; ++j) rt[j] = bf2f((ushort_t)u[j]);
    }
    float4 b0 = *(const float4*)(bias + c0);
    float4 b1 = *(const float4*)(bias + c0 + 4);
    float bs[8] = {b0.x, b0.y, b0.z, b0.w, b1.x, b1.y, b1.z, b1.w};
    unsigned pk[4];
#pragma unroll
    for (int j = 0; j < 4; ++j) {
      float v0 = fmaxf(a[2 * j] * YSI + rt[2 * j] + bs[2 * j], 0.f);
      float v1 = fmaxf(a[2 * j + 1] * YSI + rt[2 * j + 1] + bs[2 * j + 1], 0.f);
      pk[j] = (unsigned)f2bf(v0) | ((unsigned)f2bf(v1) << 16);
    }
    *(uint4*)(xbw + (size_t)d * 256 + xoff + c0) = make_uint4(pk[0], pk[1], pk[2], pk[3]);
  }
}

// Layer-3 aggregation + fused relu + log_softmax over 384 cols; writes d_out.
__global__ __launch_bounds__(256) void aggrsmq_k(const int* __restrict__ off,
                                                 const uint2* __restrict__ payload,
                                                 const unsigned char* __restrict__ hrq,
                                                 const ushort_t* __restrict__ rootb,
                                                 const float* __restrict__ bias,
                                                 const ushort_t* __restrict__ xb,
                                                 float* __restrict__ out) {
  __shared__ float hl[4][128];
  int wave = threadIdx.x >> 6, lane = threadIdx.x & 63;
  int d = blockIdx.x * 4 + wave;
  if (d >= NN) return;
  int beg = off[d], end = off[d + 1];
  int g = lane >> 4, q = lane & 15;
  int c0 = q * 8;
  float a[8] = {};
  int i = beg + g;
  for (; i + 4 < end; i += 8) {
    uint2 pA = payload[i], pB = payload[i + 4];
    uint2 vA = *(const uint2*)(hrq + ((size_t)(pA.x >> 20) * NN + (pA.x & 0xFFFFFu)) * CC + c0);
    uint2 vB = *(const uint2*)(hrq + ((size_t)(pB.x >> 20) * NN + (pB.x & 0xFFFFFu)) * CC + c0);
    acc8(a, vA.x, vA.y, __uint_as_float(pA.y));
    acc8(a, vB.x, vB.y, __uint_as_float(pB.y));
  }
  if (i < end) {
    uint2 p = payload[i];
    uint2 v = *(const uint2*)(hrq + ((size_t)(p.x >> 20) * NN + (p.x & 0xFFFFFu)) * CC + c0);
    acc8(a, v.x, v.y, __uint_as_float(p.y));
  }
#pragma unroll
  for (int j = 0; j < 8; ++j) {
    a[j] += __shfl_xor(a[j], 16);
    a[j] += __shfl_xor(a[j], 32);
  }
  if (g == 0) {
    u16x8 u = *(const u16x8*)(rootb + (size_t)d * CC + c0);
    float4 b0 = *(const float4*)(bias + c0);
    float4 b1 = *(const float4*)(bias + c0 + 4);
    float bs[8] = {b0.x, b0.y, b0.z, b0.w, b1.x, b1.y, b1.z, b1.w};
    float h[8];
#pragma unroll
    for (int j = 0; j < 8; ++j)
      h[j] = fmaxf(a[j] * YSI + bf2f((ushort_t)u[j]) + bs[j], 0.f);
    *(f32x4*)(&hl[wave][c0]) = (f32x4){h[0], h[1], h[2], h[3]};
    *(f32x4*)(&hl[wave][c0 + 4]) = (f32x4){h[4], h[5], h[6], h[7]};
  }
  // intra-wave ds_write -> ds_read (in order); no block barrier needed
  float vals[6];
#pragma unroll
  for (int jj = 0; jj < 4; ++jj)
    vals[jj] = bf2f(xb[(size_t)d * 256 + jj * 64 + lane]);
  vals[4] = hl[wave][lane];
  vals[5] = hl[wave][64 + lane];
  float m = vals[0];
#pragma unroll
  for (int jj = 1; jj < 6; ++jj) m = fmaxf(m, vals[jj]);
#pragma unroll
  for (int o = 32; o > 0; o >>= 1) m = fmaxf(m, __shfl_xor(m, o));
  float ssum = 0.f;
#pragma unroll
  for (int jj = 0; jj < 6; ++jj) ssum += expf(vals[jj] - m);
#pragma unroll
  for (int o = 32; o > 0; o >>= 1) ssum += __shfl_xor(ssum, o);
  float ls = logf(ssum);
#pragma unroll
  for (int jj = 0; jj < 6; ++jj)
    out[(size_t)d * H3C + jj * 64 + lane] = vals[jj] - m - ls;
}

// Fragment-major weights for 5 slots (0..3 = basis V_b [K_IN,128], 4 = root).
template <int K_IN>
__global__ void makew5_k(const float* __restrict__ basis, const float* __restrict__ root,
                         ushort_t* __restrict__ Wt) {
  int f = blockIdx.x * 256 + threadIdx.x;
  constexpr int KD = K_IN / 32;
  int tot = 5 * KD * 8 * 64;
  if (f >= tot) return;
  int l = f & 63;
  int fi = f >> 6;
  int cb = fi & 7;
  int rem = fi >> 3;
  int kk = rem & (KD - 1);
  int s = rem / KD;
  int fr = l & 15, fq = l >> 4;
  int c = cb * 16 + fr;
  int k0 = kk * 32 + fq * 8;
  ushort_t o[8];
#pragma unroll
  for (int j = 0; j < 8; ++j) {
    int k = k0 + j;
    float v = (s < 4) ? basis[((size_t)s * K_IN + k) * CC + c]
                      : root[(size_t)k * CC + c];
    o[j] = f2bf(v);
  }
  *(u16x8*)(Wt + (size_t)f * 8) = *(const u16x8*)o;
}

// y GEMM, BK=128: per slot s (blockIdx.y): y_s = x @ W_s.  s<4 -> fp8*YS into
// yq (LDS repack); s==4 -> bf16 yroot.  Block 64r x 128c, 4 waves 2x2.
// One barrier pair per 128-wide K slab (32 MFMA/wave/step).
template <int K_IN>
__global__ __launch_bounds__(256) void gemmy_k(const ushort_t* __restrict__ xb,
                                               const ushort_t* __restrict__ Wt,
                                               unsigned char* __restrict__ yq,
                                               ushort_t* __restrict__ yroot) {
  constexpr int NSTEPS = K_IN / 128;  // 1 or 2
  constexpr int KD = K_IN / 32;
  constexpr int XST = 136;  // X LDS row stride (u16): 128 + 8 pad
  __shared__ char smem[64 * XST * 2 + 128 * 128 * 2];  // 17408 + 32768 = 50176 B
  ushort_t* xs = (ushort_t*)smem;
  ushort_t* wls = (ushort_t*)(smem + 64 * XST * 2);
  int t = threadIdx.x;
  int wave = t >> 6, lane = t & 63;
  int wr = wave >> 1, wc = wave & 1;
  int fr = lane & 15, fq = lane >> 4;
  int row0 = blockIdx.x * 64;
  int s = blockIdx.y;

  u16x8 xreg[4], wreg[8];

#define STAGE(step)                                                              \
  {                                                                              \
    _Pragma("unroll") for (int qq = 0; qq < 4; ++qq) {                           \
      int cid = t + qq * 256;                                                    \
      int row = cid >> 4, seg = cid & 15;                                        \
      int gr = row0 + row;                                                       \
      if (gr >= NN) gr = NN - 1;                                                 \
      xreg[qq] = *(const u16x8*)(xb + (size_t)gr * 256 + (step) * 128 + seg * 8);\
    }                                                                            \
    const ushort_t* bsrc = Wt + ((size_t)s * KD + (step) * 4) * 4096;            \
    _Pragma("unroll") for (int qq = 0; qq < 8; ++qq)                             \
        wreg[qq] = *(const u16x8*)(bsrc + (size_t)(t + qq * 256) * 8);           \
  }

  f32x4 acc[2][4];
#pragma unroll
  for (int rf = 0; rf < 2; ++rf)
#pragma unroll
    for (int cb = 0; cb < 4; ++cb) acc[rf][cb] = (f32x4){0.f, 0.f, 0.f, 0.f};

  STAGE(0);
  for (int step = 0; step < NSTEPS; ++step) {
    __syncthreads();
#pragma unroll
    for (int qq = 0; qq < 4; ++qq) {
      int cid = t + qq * 256;
      *(u16x8*)(xs + (cid >> 4) * XST + (cid & 15) * 8) = xreg[qq];
    }
#pragma unroll
    for (int qq = 0; qq < 8; ++qq)
      *(u16x8*)(wls + (size_t)(t + qq * 256) * 8) = wreg[qq];
    __syncthreads();
    if (step + 1 < NSTEPS) STAGE(step + 1);
#pragma unroll
    for (int kk = 0; kk < 4; ++kk) {
      bf16x8 a0 = *(const bf16x8*)(xs + (wr * 32 + fr) * XST + kk * 32 + fq * 8);
      bf16x8 a1 = *(const bf16x8*)(xs + (wr * 32 + 16 + fr) * XST + kk * 32 + fq * 8);
#pragma unroll
      for (int cb = 0; cb < 4; ++cb) {
        bf16x8 b = *(const bf16x8*)(wls + ((kk * 8 + wc * 4 + cb) * 64 + lane) * 8);
        acc[0][cb] = __builtin_amdgcn_mfma_f32_16x16x32_bf16(a0, b, acc[0][cb], 0, 0, 0);
        acc[1][cb] = __builtin_amdgcn_mfma_f32_16x16x32_bf16(a1, b, acc[1][cb], 0, 0, 0);
      }
    }
  }
#undef STAGE

  if (s == 4) {
#pragma unroll
    for (int rf = 0; rf < 2; ++rf)
#pragma unroll
      for (int cb = 0; cb < 4; ++cb) {
        int c = wc * 64 + cb * 16 + fr;
#pragma unroll
        for (int j = 0; j < 4; ++j) {
          int n = row0 + wr * 32 + rf * 16 + fq * 4 + j;
          if (n < NN) yroot[(size_t)n * CC + c] = f2bf(acc[rf][cb][j]);
        }
      }
  } else {
    __syncthreads();
    float* rp = (float*)smem;  // [64][132] f32 = 33792 B <= 50176
#pragma unroll
    for (int rf = 0; rf < 2; ++rf)
#pragma unroll
      for (int cb = 0; cb < 4; ++cb)
#pragma unroll
        for (int j = 0; j < 4; ++j)
          rp[(wr * 32 + rf * 16 + fq * 4 + j) * 132 + wc * 64 + cb * 16 + fr] = acc[rf][cb][j];
    __syncthreads();
    int row = t & 63, c0 = (t >> 6) * 32;
    int gr = row0 + row;
    if (gr < NN) {
      const float* src = rp + row * 132 + c0;
      unsigned ub[8];
#pragma unroll
      for (int qq = 0; qq < 8; ++qq) {
        float4 v = *(const float4*)(src + qq * 4);
        int pk = __builtin_amdgcn_cvt_pk_fp8_f32(v.x * YS, v.y * YS, 0, false);
        pk = __builtin_amdgcn_cvt_pk_fp8_f32(v.z * YS, v.w * YS, pk, true);
        ub[qq] = (unsigned)pk;
      }
      unsigned char* dst = yq + (size_t)gr * 512 + s * 128 + c0;
      *(uint4*)dst = make_uint4(ub[0], ub[1], ub[2], ub[3]);
      *(uint4*)(dst + 16) = make_uint4(ub[4], ub[5], ub[6], ub[7]);
    }
  }
}

extern "C" void kernel_launch(void* const* d_in, const int* in_sizes, int n_in,
                              void* d_out, int out_size, void* d_ws, size_t ws_size,
                              hipStream_t stream) {
  const int* ei = (const int*)d_in[0];
  const int* et = (const int*)d_in[1];
  const float* basis1 = (const float*)d_in[2];
  const float* comp1 = (const float*)d_in[3];
  const float* root1 = (const float*)d_in[4];
  const float* bias1 = (const float*)d_in[5];
  const float* basis_b0 = (const float*)d_in[6];
  const float* comp_b0 = (const float*)d_in[7];
  const float* root_b0 = (const float*)d_in[8];
  const float* bias_b0 = (const float*)d_in[9];
  const float* basis_b1 = (const float*)d_in[10];
  const float* comp_b1 = (const float*)d_in[11];
  const float* root_b1 = (const float*)d_in[12];
  const float* bias_b1 = (const float*)d_in[13];
  float* out = (float*)d_out;  // [N][384]
  char* ws = (char*)d_ws;

  uint2* payload = (uint2*)ws;                            // 4 MB
  ushort_t* yroot = (ushort_t*)(payload + EE);            // N*128 bf16 = 12.8 MB
  ushort_t* xb = yroot + (size_t)NN * CC;                 // N*256 bf16 = 25.6 MB
  ushort_t* wt = xb + (size_t)NN * 256;                   // 327680 u16 = 0.66 MB
  unsigned char* yq = (unsigned char*)(wt + 327680);      // N*512 fp8 = 25.6 MB
  unsigned char* hrq = yq + (size_t)NN * 512;             // R*N*C fp8 = 51.2 MB
  int* cnt_rd = (int*)(hrq + (size_t)RR * NN * CC);       // R*N int
  int* cur = cnt_rd + (size_t)RR * NN;                    // N int
  int* off = cur + NN;                                    // N+1 int
  int* bsum = off + NN + 1;
  int* bbase = bsum + 256;
  size_t need = (size_t)((char*)(bbase + 256) - ws);
  if (ws_size < need) return;

  // --- CSR build ---
  zero_int_k<<<(RR * NN + 255) / 256, 256, 0, stream>>>(cnt_rd, RR * NN);
  count_k<<<(EE + 255) / 256, 256, 0, stream>>>(ei, et, cnt_rd);
  scanA_k<<<NB, 256, 0, stream>>>(cnt_rd, off, bsum);
  scanB_k<<<1, 256, 0, stream>>>(bsum, bbase);
  scanC_k<<<NB, 256, 0, stream>>>(off, bbase, cur);
  fill_k<<<(EE + 255) / 256, 256, 0, stream>>>(ei, et, cnt_rd, cur, payload);

  const int AG_BLKS = (NN + 3) / 4;
  const int HQ_BLKS = (NN * 32 + 255) / 256;  // 6250
  const int GE_BLKS = (NN + 63) / 64;         // 782
  dim3 gy(GE_BLKS, 5);

  // --- layer 1: message table straight from basis1; f32 root1 ---
  makehr1q_k<<<HQ_BLKS, 256, 0, stream>>>(basis1, comp1, hrq);
  aggrq_k<true><<<AG_BLKS, 256, 0, stream>>>(off, payload, hrq, root1, nullptr, bias1, xb, 0);

  // --- layer 2 (K=128) ---
  makew5_k<128><<<(5 * 4 * 8 * 64 + 255) / 256, 256, 0, stream>>>(basis_b0, root_b0, wt);
  gemmy_k<128><<<gy, 256, 0, stream>>>(xb, wt, yq, yroot);
  makehrq_k<<<HQ_BLKS, 256, 0, stream>>>(yq, comp_b0, hrq);
  aggrq_k<false><<<AG_BLKS, 256, 0, stream>>>(off, payload, hrq, nullptr, yroot, bias_b0, xb, CC);

  // --- layer 3 (K=256) + fused log_softmax ---
  makew5_k<256><<<(5 * 8 * 8 * 64 + 255) / 256, 256, 0, stream>>>(basis_b1, root_b1, wt);
  gemmy_k<256><<<gy, 256, 0, stream>>>(xb, wt, yq, yroot);
  makehrq_k<<<HQ_BLKS, 256, 0, stream>>>(yq, comp_b1, hrq);
  aggrsmq_k<<<AG_BLKS, 256, 0, stream>>>(off, payload, hrq, yroot, bias_b1, xb, out);
}

// Round 12
// 276.741 us; speedup vs baseline: 1.0090x; 1.0090x over previous
//
#include <hip/hip_runtime.h>
#include <cstdint>
#include <cstddef>

#define NN 50000
#define EE 500000
#define RR 8
#define CC 128
#define BB 4
#define H3C 384
#define NB 196  // ceil(NN/256)
#define YS 64.0f
#define YSI (1.0f / 64.0f)

typedef unsigned short ushort_t;
typedef __bf16 bf16x8 __attribute__((ext_vector_type(8)));
typedef float f32x4 __attribute__((ext_vector_type(4)));
typedef float f32x2 __attribute__((ext_vector_type(2)));
typedef unsigned short u16x8 __attribute__((ext_vector_type(8)));

static __device__ __forceinline__ ushort_t f2bf(float f) {
  unsigned u = __float_as_uint(f);
  unsigned r = (u + 0x7fffu + ((u >> 16) & 1u)) >> 16;
  return (ushort_t)r;
}
static __device__ __forceinline__ float bf2f(ushort_t u) {
  return __uint_as_float(((unsigned)u) << 16);
}

// accumulate 8 fp8 channels (2 dwords) with weight w
static __device__ __forceinline__ void acc8(float* a, unsigned vx, unsigned vy, float w) {
  f32x2 t;
  t = __builtin_amdgcn_cvt_pk_f32_fp8(vx, false); a[0] += w * t.x; a[1] += w * t.y;
  t = __builtin_amdgcn_cvt_pk_f32_fp8(vx, true);  a[2] += w * t.x; a[3] += w * t.y;
  t = __builtin_amdgcn_cvt_pk_f32_fp8(vy, false); a[4] += w * t.x; a[5] += w * t.y;
  t = __builtin_amdgcn_cvt_pk_f32_fp8(vy, true);  a[6] += w * t.x; a[7] += w * t.y;
}

__global__ void zero_int_k(int* p, int n) {
  int i = blockIdx.x * 256 + threadIdx.x;
  if (i < n) p[i] = 0;
}

__global__ void count_k(const int* __restrict__ ei, const int* __restrict__ et, int* cnt) {
  int e = blockIdx.x * 256 + threadIdx.x;
  if (e >= EE) return;
  int d = ei[EE + e];
  int r = et[e];
  atomicAdd(&cnt[r * NN + d], 1);
}

__global__ __launch_bounds__(256) void scanA_k(const int* __restrict__ cnt_rd, int* off, int* bsum) {
  __shared__ int s[256];
  int t = threadIdx.x;
  int i = blockIdx.x * 256 + t;
  int v = 0;
  if (i < NN) {
#pragma unroll
    for (int r = 0; r < RR; ++r) v += cnt_rd[r * NN + i];
  }
  s[t] = v;
  __syncthreads();
  for (int d = 1; d < 256; d <<= 1) {
    int x = (t >= d) ? s[t - d] : 0;
    __syncthreads();
    s[t] += x;
    __syncthreads();
  }
  if (i < NN) off[i] = s[t] - v;
  if (t == 255) bsum[blockIdx.x] = s[255];
}

__global__ __launch_bounds__(256) void scanB_k(const int* __restrict__ bsum, int* bbase) {
  __shared__ int s[256];
  int t = threadIdx.x;
  int v = (t < NB) ? bsum[t] : 0;
  s[t] = v;
  __syncthreads();
  for (int d = 1; d < 256; d <<= 1) {
    int x = (t >= d) ? s[t - d] : 0;
    __syncthreads();
    s[t] += x;
    __syncthreads();
  }
  if (t < NB) bbase[t] = s[t] - v;
}

// finalize offsets AND pre-load cursor array with the start offset
__global__ void scanC_k(int* off, const int* __restrict__ bbase, int* cur) {
  int i = blockIdx.x * 256 + threadIdx.x;
  if (i < NN) {
    int v = off[i] + bbase[i >> 8];
    off[i] = v;
    cur[i] = v;
  }
  if (i == 0) off[NN] = EE;
}

// Scatter edges into CSR slots; payload = {src | (r<<20), bits(1/max(cnt_rd,1))}.
__global__ void fill_k(const int* __restrict__ ei, const int* __restrict__ et,
                       const int* __restrict__ cnt_rd, int* cur, uint2* __restrict__ payload) {
  int e = blockIdx.x * 256 + threadIdx.x;
  if (e >= EE) return;
  int s = ei[e], d = ei[EE + e], r = et[e];
  int pos = atomicAdd(&cur[d], 1);
  float w = 1.0f / (float)max(cnt_rd[r * NN + d], 1);
  payload[pos] = make_uint2((unsigned)s | ((unsigned)r << 20), __float_as_uint(w));
}

// Layer-1 message table: hrq[r][n][c] = fp8(YS * sum_b comp1[r][b]*basis1[b][n][c])
__global__ void makehr1q_k(const float* __restrict__ basis1, const float* __restrict__ comp1,
                           unsigned char* __restrict__ hrq) {
  __shared__ float comps[RR * BB];
  if (threadIdx.x < RR * BB) comps[threadIdx.x] = comp1[threadIdx.x] * YS;
  __syncthreads();
  int idx = blockIdx.x * 256 + threadIdx.x;  // n*32 + c4
  if (idx >= NN * 32) return;
  int n = idx >> 5, c0 = (idx & 31) * 4;
  float4 y[BB];
#pragma unroll
  for (int b = 0; b < BB; ++b)
    y[b] = *(const float4*)(basis1 + ((size_t)b * NN + n) * CC + c0);
#pragma unroll
  for (int r = 0; r < RR; ++r) {
    float k0 = comps[r * BB + 0], k1 = comps[r * BB + 1];
    float k2 = comps[r * BB + 2], k3 = comps[r * BB + 3];
    float v0 = k0 * y[0].x + k1 * y[1].x + k2 * y[2].x + k3 * y[3].x;
    float v1 = k0 * y[0].y + k1 * y[1].y + k2 * y[2].y + k3 * y[3].y;
    float v2 = k0 * y[0].z + k1 * y[1].z + k2 * y[2].z + k3 * y[3].z;
    float v3 = k0 * y[0].w + k1 * y[1].w + k2 * y[2].w + k3 * y[3].w;
    int pk = __builtin_amdgcn_cvt_pk_fp8_f32(v0, v1, 0, false);
    pk = __builtin_amdgcn_cvt_pk_fp8_f32(v2, v3, pk, true);
    *(unsigned*)(hrq + ((size_t)r * NN + n) * CC + c0) = (unsigned)pk;
  }
}

// Layers 2/3 message table: hrq[r][n][c] = fp8( sum_b comp[r][b] * yq_b[n][c] )
__global__ void makehrq_k(const unsigned char* __restrict__ yq, const float* __restrict__ comp,
                          unsigned char* __restrict__ hrq) {
  __shared__ float comps[RR * BB];
  if (threadIdx.x < RR * BB) comps[threadIdx.x] = comp[threadIdx.x];
  __syncthreads();
  int idx = blockIdx.x * 256 + threadIdx.x;  // n*32 + c4
  if (idx >= NN * 32) return;
  int n = idx >> 5, c0 = (idx & 31) * 4;
  const unsigned char* yr = yq + (size_t)n * 512 + c0;
  float y[BB][4];
#pragma unroll
  for (int b = 0; b < BB; ++b) {
    unsigned u = *(const unsigned*)(yr + b * 128);
    f32x2 lo = __builtin_amdgcn_cvt_pk_f32_fp8(u, false);
    f32x2 hi = __builtin_amdgcn_cvt_pk_f32_fp8(u, true);
    y[b][0] = lo.x; y[b][1] = lo.y; y[b][2] = hi.x; y[b][3] = hi.y;
  }
#pragma unroll
  for (int r = 0; r < RR; ++r) {
    float k0 = comps[r * BB + 0], k1 = comps[r * BB + 1];
    float k2 = comps[r * BB + 2], k3 = comps[r * BB + 3];
    float v0 = k0 * y[0][0] + k1 * y[1][0] + k2 * y[2][0] + k3 * y[3][0];
    float v1 = k0 * y[0][1] + k1 * y[1][1] + k2 * y[2][1] + k3 * y[3][1];
    float v2 = k0 * y[0][2] + k1 * y[1][2] + k2 * y[2][2] + k3 * y[3][2];
    float v3 = k0 * y[0][3] + k1 * y[1][3] + k2 * y[2][3] + k3 * y[3][3];
    int pk = __builtin_amdgcn_cvt_pk_fp8_f32(v0, v1, 0, false);
    pk = __builtin_amdgcn_cvt_pk_fp8_f32(v2, v3, pk, true);
    *(unsigned*)(hrq + ((size_t)r * NN + n) * CC + c0) = (unsigned)pk;
  }
}

// Aggregation: one wave per node; 4 quarter-wave groups each own an edge
// stream (4 edges in flight); lane handles 8 channels (8B gather per edge).
template <bool ROOTF32>
__global__ __launch_bounds__(256) void aggrq_k(const int* __restrict__ off,
                                               const uint2* __restrict__ payload,
                                               const unsigned char* __restrict__ hrq,
                                               const float* __restrict__ rootf,
                                               const ushort_t* __restrict__ rootb,
                                               const float* __restrict__ bias,
                                               ushort_t* __restrict__ xbw, int xoff) {
  int wave = threadIdx.x >> 6, lane = threadIdx.x & 63;
  int d = blockIdx.x * 4 + wave;
  if (d >= NN) return;
  int beg = off[d], end = off[d + 1];
  int g = lane >> 4, q = lane & 15;
  int c0 = q * 8;
  float a[8] = {};
  int i = beg + g;
  for (; i + 4 < end; i += 8) {
    uint2 pA = payload[i], pB = payload[i + 4];
    uint2 vA = *(const uint2*)(hrq + ((size_t)(pA.x >> 20) * NN + (pA.x & 0xFFFFFu)) * CC + c0);
    uint2 vB = *(const uint2*)(hrq + ((size_t)(pB.x >> 20) * NN + (pB.x & 0xFFFFFu)) * CC + c0);
    acc8(a, vA.x, vA.y, __uint_as_float(pA.y));
    acc8(a, vB.x, vB.y, __uint_as_float(pB.y));
  }
  if (i < end) {
    uint2 p = payload[i];
    uint2 v = *(const uint2*)(hrq + ((size_t)(p.x >> 20) * NN + (p.x & 0xFFFFFu)) * CC + c0);
    acc8(a, v.x, v.y, __uint_as_float(p.y));
  }
#pragma unroll
  for (int j = 0; j < 8; ++j) {
    a[j] += __shfl_xor(a[j], 16);
    a[j] += __shfl_xor(a[j], 32);
  }
  if (g == 0) {
    float rt[8];
    if (ROOTF32) {
      float4 r0 = *(const float4*)(rootf + (size_t)d * CC + c0);
      float4 r1 = *(const float4*)(rootf + (size_t)d * CC + c0 + 4);
      rt[0] = r0.x; rt[1] = r0.y; rt[2] = r0.z; rt[3] = r0.w;
      rt[4] = r1.x; rt[5] = r1.y; rt[6] = r1.z; rt[7] = r1.w;
    } else {
      u16x8 u = *(const u16x8*)(rootb + (size_t)d * CC + c0);
#pragma unroll
      for (int j = 0; j < 8; ++j) rt[j] = bf2f((ushort_t)u[j]);
    }
    float4 b0 = *(const float4*)(bias + c0);
    float4 b1 = *(const float4*)(bias + c0 + 4);
    float bs[8] = {b0.x, b0.y, b0.z, b0.w, b1.x, b1.y, b1.z, b1.w};
    unsigned pk[4];
#pragma unroll
    for (int j = 0; j < 4; ++j) {
      float v0 = fmaxf(a[2 * j] * YSI + rt[2 * j] + bs[2 * j], 0.f);
      float v1 = fmaxf(a[2 * j + 1] * YSI + rt[2 * j + 1] + bs[2 * j + 1], 0.f);
      pk[j] = (unsigned)f2bf(v0) | ((unsigned)f2bf(v1) << 16);
    }
    *(uint4*)(xbw + (size_t)d * 256 + xoff + c0) = make_uint4(pk[0], pk[1], pk[2], pk[3]);
  }
}

// Layer-3 aggregation + fused relu + log_softmax over 384 cols; writes d_out.
__global__ __launch_bounds__(256) void aggrsmq_k(const int* __restrict__ off,
                                                 const uint2* __restrict__ payload,
                                                 const unsigned char* __restrict__ hrq,
                                                 const ushort_t* __restrict__ rootb,
                                                 const float* __restrict__ bias,
                                                 const ushort_t* __restrict__ xb,
                                                 float* __restrict__ out) {
  __shared__ float hl[4][128];
  int wave = threadIdx.x >> 6, lane = threadIdx.x & 63;
  int d = blockIdx.x * 4 + wave;
  if (d >= NN) return;
  int beg = off[d], end = off[d + 1];
  int g = lane >> 4, q = lane & 15;
  int c0 = q * 8;
  float a[8] = {};
  int i = beg + g;
  for (; i + 4 < end; i += 8) {
    uint2 pA = payload[i], pB = payload[i + 4];
    uint2 vA = *(const uint2*)(hrq + ((size_t)(pA.x >> 20) * NN + (pA.x & 0xFFFFFu)) * CC + c0);
    uint2 vB = *(const uint2*)(hrq + ((size_t)(pB.x >> 20) * NN + (pB.x & 0xFFFFFu)) * CC + c0);
    acc8(a, vA.x, vA.y, __uint_as_float(pA.y));
    acc8(a, vB.x, vB.y, __uint_as_float(pB.y));
  }
  if (i < end) {
    uint2 p = payload[i];
    uint2 v = *(const uint2*)(hrq + ((size_t)(p.x >> 20) * NN + (p.x & 0xFFFFFu)) * CC + c0);
    acc8(a, v.x, v.y, __uint_as_float(p.y));
  }
#pragma unroll
  for (int j = 0; j < 8; ++j) {
    a[j] += __shfl_xor(a[j], 16);
    a[j] += __shfl_xor(a[j], 32);
  }
  if (g == 0) {
    u16x8 u = *(const u16x8*)(rootb + (size_t)d * CC + c0);
    float4 b0 = *(const float4*)(bias + c0);
    float4 b1 = *(const float4*)(bias + c0 + 4);
    float bs[8] = {b0.x, b0.y, b0.z, b0.w, b1.x, b1.y, b1.z, b1.w};
    float h[8];
#pragma unroll
    for (int j = 0; j < 8; ++j)
      h[j] = fmaxf(a[j] * YSI + bf2f((ushort_t)u[j]) + bs[j], 0.f);
    *(f32x4*)(&hl[wave][c0]) = (f32x4){h[0], h[1], h[2], h[3]};
    *(f32x4*)(&hl[wave][c0 + 4]) = (f32x4){h[4], h[5], h[6], h[7]};
  }
  // intra-wave ds_write -> ds_read (in order); no block barrier needed
  float vals[6];
#pragma unroll
  for (int jj = 0; jj < 4; ++jj)
    vals[jj] = bf2f(xb[(size_t)d * 256 + jj * 64 + lane]);
  vals[4] = hl[wave][lane];
  vals[5] = hl[wave][64 + lane];
  float m = vals[0];
#pragma unroll
  for (int jj = 1; jj < 6; ++jj) m = fmaxf(m, vals[jj]);
#pragma unroll
  for (int o = 32; o > 0; o >>= 1) m = fmaxf(m, __shfl_xor(m, o));
  float ssum = 0.f;
#pragma unroll
  for (int jj = 0; jj < 6; ++jj) ssum += expf(vals[jj] - m);
#pragma unroll
  for (int o = 32; o > 0; o >>= 1) ssum += __shfl_xor(ssum, o);
  float ls = logf(ssum);
#pragma unroll
  for (int jj = 0; jj < 6; ++jj)
    out[(size_t)d * H3C + jj * 64 + lane] = vals[jj] - m - ls;
}

// Fragment-major weights for 5 slots (0..3 = basis V_b [K_IN,128], 4 = root).
template <int K_IN>
__global__ void makew5_k(const float* __restrict__ basis, const float* __restrict__ root,
                         ushort_t* __restrict__ Wt) {
  int f = blockIdx.x * 256 + threadIdx.x;
  constexpr int KD = K_IN / 32;
  int tot = 5 * KD * 8 * 64;
  if (f >= tot) return;
  int l = f & 63;
  int fi = f >> 6;
  int cb = fi & 7;
  int rem = fi >> 3;
  int kk = rem & (KD - 1);
  int s = rem / KD;
  int fr = l & 15, fq = l >> 4;
  int c = cb * 16 + fr;
  int k0 = kk * 32 + fq * 8;
  ushort_t o[8];
#pragma unroll
  for (int j = 0; j < 8; ++j) {
    int k = k0 + j;
    float v = (s < 4) ? basis[((size_t)s * K_IN + k) * CC + c]
                      : root[(size_t)k * CC + c];
    o[j] = f2bf(v);
  }
  *(u16x8*)(Wt + (size_t)f * 8) = *(const u16x8*)o;
}

// y GEMM, BK=64 (measured-best): per slot s (blockIdx.y): y_s = x @ W_s.
// s<4 -> fp8*YS into yq (LDS repack); s==4 -> bf16 yroot.
// Block 64r x 128c, 4 waves 2x2, reg-staged double buffering.
template <int K_IN>
__global__ __launch_bounds__(256) void gemmy_k(const ushort_t* __restrict__ xb,
                                               const ushort_t* __restrict__ Wt,
                                               unsigned char* __restrict__ yq,
                                               ushort_t* __restrict__ yroot) {
  constexpr int NSTEPS = K_IN / 64;
  constexpr int XST = 72;
  __shared__ char smem[64 * 132 * 4];  // 33792 B; phases: (xs|wls) then repack
  ushort_t* xs = (ushort_t*)smem;                     // 64*72*2 = 9216 B
  ushort_t* wls = (ushort_t*)(smem + 64 * XST * 2);   // 16384 B
  int t = threadIdx.x;
  int wave = t >> 6, lane = t & 63;
  int wr = wave >> 1, wc = wave & 1;
  int fr = lane & 15, fq = lane >> 4;
  int row0 = blockIdx.x * 64;
  int s = blockIdx.y;
  const ushort_t* wslot = Wt + (size_t)s * (K_IN * 128);

  u16x8 areg0, areg1, breg[4];
  auto stage = [&](int step) {
    int seg = t & 7;
    int row = t >> 3;
    int gr = row0 + row;
    if (gr >= NN) gr = NN - 1;
    areg0 = *(const u16x8*)(xb + (size_t)gr * 256 + step * 64 + seg * 8);
    row = (t + 256) >> 3;
    gr = row0 + row;
    if (gr >= NN) gr = NN - 1;
    areg1 = *(const u16x8*)(xb + (size_t)gr * 256 + step * 64 + seg * 8);
    const ushort_t* bsrc = wslot + (size_t)step * 8192;
#pragma unroll
    for (int q = 0; q < 4; ++q)
      breg[q] = *(const u16x8*)(bsrc + (size_t)(t + q * 256) * 8);
  };

  f32x4 acc[2][4];
#pragma unroll
  for (int rf = 0; rf < 2; ++rf)
#pragma unroll
    for (int cb = 0; cb < 4; ++cb) acc[rf][cb] = (f32x4){0.f, 0.f, 0.f, 0.f};

  stage(0);
  for (int step = 0; step < NSTEPS; ++step) {
    __syncthreads();
    {
      int seg = t & 7;
      *(u16x8*)(xs + (t >> 3) * XST + seg * 8) = areg0;
      *(u16x8*)(xs + ((t + 256) >> 3) * XST + seg * 8) = areg1;
    }
#pragma unroll
    for (int q = 0; q < 4; ++q)
      *(u16x8*)(wls + (size_t)(t + q * 256) * 8) = breg[q];
    __syncthreads();
    if (step + 1 < NSTEPS) stage(step + 1);
#pragma unroll
    for (int kk = 0; kk < 2; ++kk) {
      bf16x8 a0 = *(const bf16x8*)(xs + (wr * 32 + fr) * XST + kk * 32 + fq * 8);
      bf16x8 a1 = *(const bf16x8*)(xs + (wr * 32 + 16 + fr) * XST + kk * 32 + fq * 8);
#pragma unroll
      for (int cb = 0; cb < 4; ++cb) {
        bf16x8 b = *(const bf16x8*)(wls + ((kk * 8 + wc * 4 + cb) * 64 + lane) * 8);
        acc[0][cb] = __builtin_amdgcn_mfma_f32_16x16x32_bf16(a0, b, acc[0][cb], 0, 0, 0);
        acc[1][cb] = __builtin_amdgcn_mfma_f32_16x16x32_bf16(a1, b, acc[1][cb], 0, 0, 0);
      }
    }
  }

  if (s == 4) {
#pragma unroll
    for (int rf = 0; rf < 2; ++rf)
#pragma unroll
      for (int cb = 0; cb < 4; ++cb) {
        int c = wc * 64 + cb * 16 + fr;
#pragma unroll
        for (int j = 0; j < 4; ++j) {
          int n = row0 + wr * 32 + rf * 16 + fq * 4 + j;
          if (n < NN) yroot[(size_t)n * CC + c] = f2bf(acc[rf][cb][j]);
        }
      }
  } else {
    __syncthreads();
    float* rp = (float*)smem;  // [64][132]
#pragma unroll
    for (int rf = 0; rf < 2; ++rf)
#pragma unroll
      for (int cb = 0; cb < 4; ++cb)
#pragma unroll
        for (int j = 0; j < 4; ++j)
          rp[(wr * 32 + rf * 16 + fq * 4 + j) * 132 + wc * 64 + cb * 16 + fr] = acc[rf][cb][j];
    __syncthreads();
    int row = t & 63, c0 = (t >> 6) * 32;
    int gr = row0 + row;
    if (gr < NN) {
      const float* src = rp + row * 132 + c0;
      unsigned ub[8];
#pragma unroll
      for (int q = 0; q < 8; ++q) {
        float4 v = *(const float4*)(src + q * 4);
        int pk = __builtin_amdgcn_cvt_pk_fp8_f32(v.x * YS, v.y * YS, 0, false);
        pk = __builtin_amdgcn_cvt_pk_fp8_f32(v.z * YS, v.w * YS, pk, true);
        ub[q] = (unsigned)pk;
      }
      unsigned char* dst = yq + (size_t)gr * 512 + s * 128 + c0;
      *(uint4*)dst = make_uint4(ub[0], ub[1], ub[2], ub[3]);
      *(uint4*)(dst + 16) = make_uint4(ub[4], ub[5], ub[6], ub[7]);
    }
  }
}

extern "C" void kernel_launch(void* const* d_in, const int* in_sizes, int n_in,
                              void* d_out, int out_size, void* d_ws, size_t ws_size,
                              hipStream_t stream) {
  const int* ei = (const int*)d_in[0];
  const int* et = (const int*)d_in[1];
  const float* basis1 = (const float*)d_in[2];
  const float* comp1 = (const float*)d_in[3];
  const float* root1 = (const float*)d_in[4];
  const float* bias1 = (const float*)d_in[5];
  const float* basis_b0 = (const float*)d_in[6];
  const float* comp_b0 = (const float*)d_in[7];
  const float* root_b0 = (const float*)d_in[8];
  const float* bias_b0 = (const float*)d_in[9];
  const float* basis_b1 = (const float*)d_in[10];
  const float* comp_b1 = (const float*)d_in[11];
  const float* root_b1 = (const float*)d_in[12];
  const float* bias_b1 = (const float*)d_in[13];
  float* out = (float*)d_out;  // [N][384]
  char* ws = (char*)d_ws;

  uint2* payload = (uint2*)ws;                            // 4 MB
  ushort_t* yroot = (ushort_t*)(payload + EE);            // N*128 bf16 = 12.8 MB
  ushort_t* xb = yroot + (size_t)NN * CC;                 // N*256 bf16 = 25.6 MB
  ushort_t* wt = xb + (size_t)NN * 256;                   // 327680 u16 = 0.66 MB
  unsigned char* yq = (unsigned char*)(wt + 327680);      // N*512 fp8 = 25.6 MB
  unsigned char* hrq = yq + (size_t)NN * 512;             // R*N*C fp8 = 51.2 MB
  int* cnt_rd = (int*)(hrq + (size_t)RR * NN * CC);       // R*N int
  int* cur = cnt_rd + (size_t)RR * NN;                    // N int
  int* off = cur + NN;                                    // N+1 int
  int* bsum = off + NN + 1;
  int* bbase = bsum + 256;
  size_t need = (size_t)((char*)(bbase + 256) - ws);
  if (ws_size < need) return;

  // --- CSR build ---
  zero_int_k<<<(RR * NN + 255) / 256, 256, 0, stream>>>(cnt_rd, RR * NN);
  count_k<<<(EE + 255) / 256, 256, 0, stream>>>(ei, et, cnt_rd);
  scanA_k<<<NB, 256, 0, stream>>>(cnt_rd, off, bsum);
  scanB_k<<<1, 256, 0, stream>>>(bsum, bbase);
  scanC_k<<<NB, 256, 0, stream>>>(off, bbase, cur);
  fill_k<<<(EE + 255) / 256, 256, 0, stream>>>(ei, et, cnt_rd, cur, payload);

  const int AG_BLKS = (NN + 3) / 4;
  const int HQ_BLKS = (NN * 32 + 255) / 256;  // 6250
  const int GE_BLKS = (NN + 63) / 64;         // 782
  dim3 gy(GE_BLKS, 5);

  // --- layer 1: message table straight from basis1; f32 root1 ---
  makehr1q_k<<<HQ_BLKS, 256, 0, stream>>>(basis1, comp1, hrq);
  aggrq_k<true><<<AG_BLKS, 256, 0, stream>>>(off, payload, hrq, root1, nullptr, bias1, xb, 0);

  // --- layer 2 (K=128) ---
  makew5_k<128><<<(5 * 4 * 8 * 64 + 255) / 256, 256, 0, stream>>>(basis_b0, root_b0, wt);
  gemmy_k<128><<<gy, 256, 0, stream>>>(xb, wt, yq, yroot);
  makehrq_k<<<HQ_BLKS, 256, 0, stream>>>(yq, comp_b0, hrq);
  aggrq_k<false><<<AG_BLKS, 256, 0, stream>>>(off, payload, hrq, nullptr, yroot, bias_b0, xb, CC);

  // --- layer 3 (K=256) + fused log_softmax ---
  makew5_k<256><<<(5 * 8 * 8 * 64 + 255) / 256, 256, 0, stream>>>(basis_b1, root_b1, wt);
  gemmy_k<256><<<gy, 256, 0, stream>>>(xb, wt, yq, yroot);
  makehrq_k<<<HQ_BLKS, 256, 0, stream>>>(yq, comp_b1, hrq);
  aggrsmq_k<<<AG_BLKS, 256, 0, stream>>>(off, payload, hrq, yroot, bias_b1, xb, out);
}